// Round 1
// baseline (2633.171 us; speedup 1.0000x reference)
//
#include <hip/hip_runtime.h>
#include <hip/hip_bf16.h>

#define BB 8
#define CC 64
#define NN 4096
#define KK 20
#define OO 64
#define TP 128           // kNN point tile
#define FMAXV 3.402823466e38f

// ---------------------------------------------------------------------------
// Kernel T: transpose x (B,C,N) -> xt (B,N,C) and per-point sq[n] = sum_c x^2
// ---------------------------------------------------------------------------
__global__ __launch_bounds__(256) void ktrans(const float* __restrict__ x,
                                              float* __restrict__ xt,
                                              float* __restrict__ sq) {
  __shared__ float tile[64][65];
  const int b = blockIdx.y, n0 = blockIdx.x * 64;
  const int lane = threadIdx.x & 63, grp = threadIdx.x >> 6;
  #pragma unroll
  for (int j = 0; j < 16; ++j) {
    int c = grp + j * 4;
    tile[c][lane] = x[((size_t)b * CC + c) * NN + n0 + lane];
  }
  __syncthreads();
  #pragma unroll
  for (int j = 0; j < 16; ++j) {
    int n = grp + j * 4;
    xt[((size_t)b * NN + n0 + n) * CC + lane] = tile[lane][n];
  }
  if (threadIdx.x < 64) {
    float s = 0.f;
    #pragma unroll
    for (int c = 0; c < 64; ++c) { float vv = tile[c][lane]; s += vv * vv; }
    sq[(size_t)b * NN + n0 + lane] = s;
  }
}

// ---------------------------------------------------------------------------
// Wave-parallel top-20 insertion. List element lives in (lv, lm) of lanes 0..19.
// th is a wave-uniform upper bound on the current max key (may be stale-high).
// Candidate set membership key is (d, m) lexicographic; m arrives increasing.
// ---------------------------------------------------------------------------
__device__ __forceinline__ void insert1(float& lv, int& lm, float& th,
                                        float dcand, int mcand, int lane) {
  unsigned long long bal = __ballot(dcand < th);
  while (bal) {
    int src = __ffsll(bal) - 1;
    bal &= bal - 1;
    float dc = __shfl(dcand, src);
    int   mc = __shfl(mcand, src);
    // butterfly argmax over list slots: max d, tie -> larger m (evict newest of ties)
    float v  = (lane < 20) ? lv : -FMAXV;
    int   mm = (lane < 20) ? lm : -2000000;
    int  pos = lane;
    #pragma unroll
    for (int off = 32; off >= 1; off >>= 1) {
      float v2 = __shfl_xor(v, off);
      int  mm2 = __shfl_xor(mm, off);
      int   p2 = __shfl_xor(pos, off);
      bool take = (v2 > v) || (v2 == v && mm2 > mm);
      if (take) { v = v2; mm = mm2; pos = p2; }
    }
    if (dc >= v) continue;         // exact re-check vs true current max
    if (lane == pos) { lv = dc; lm = mc; }
    th = v;                        // stale-but-safe bound (>= new true max)
  }
}

// ---------------------------------------------------------------------------
// Kernel KNN: per row n, rank by sq[m] - 2*dot(x_n, x_m); keep top-20 (m != n).
// Block = 4 waves; each wave owns 2 rows (row vectors in VGPRs); shared LDS tile.
// ---------------------------------------------------------------------------
__global__ __launch_bounds__(256) void kknn(const float* __restrict__ xt,
                                            const float* __restrict__ sq,
                                            int* __restrict__ knn) {
  __shared__ float tile[TP][65];
  __shared__ float ssq[TP];
  const int b = blockIdx.y;
  const int lane = threadIdx.x & 63, w = threadIdx.x >> 6;
  const int n_base = blockIdx.x * 8 + w * 2;

  float xn0[64], xn1[64];
  const float4* xr = (const float4*)(xt + ((size_t)b * NN + n_base) * CC);
  #pragma unroll
  for (int i = 0; i < 16; ++i) {
    float4 q0 = xr[i];      xn0[i*4]=q0.x; xn0[i*4+1]=q0.y; xn0[i*4+2]=q0.z; xn0[i*4+3]=q0.w;
    float4 q1 = xr[16 + i]; xn1[i*4]=q1.x; xn1[i*4+1]=q1.y; xn1[i*4+2]=q1.z; xn1[i*4+3]=q1.w;
  }
  // register-resident top-20 lists (lanes 0..19), staggered init keys
  float lv0 = FMAXV, lv1 = FMAXV;
  int   lm0 = -1 - lane, lm1 = -1 - lane;
  float th0 = FMAXV, th1 = FMAXV;

  const float4* srcb = (const float4*)(xt + (size_t)b * NN * CC);
  for (int t = 0; t < NN / TP; ++t) {
    __syncthreads();
    for (int i = threadIdx.x; i < TP * 16; i += 256) {
      float4 q = srcb[(size_t)t * TP * 16 + i];
      int p = i >> 4, c4 = (i & 15) << 2;
      tile[p][c4] = q.x; tile[p][c4+1] = q.y; tile[p][c4+2] = q.z; tile[p][c4+3] = q.w;
    }
    if (threadIdx.x < TP) ssq[threadIdx.x] = sq[(size_t)b * NN + t * TP + threadIdx.x];
    __syncthreads();

    #pragma unroll
    for (int pp = 0; pp < 2; ++pp) {
      const int p = lane + pp * 64;
      const int m = t * TP + p;
      float a0 = 0.f, a1 = 0.f;
      #pragma unroll
      for (int c = 0; c < 64; ++c) {
        float xm = tile[p][c];
        a0 += xn0[c] * xm;
        a1 += xn1[c] * xm;
      }
      float d0 = ssq[p] - 2.f * a0;
      float d1 = ssq[p] - 2.f * a1;
      if (m == n_base)     d0 = FMAXV;
      if (m == n_base + 1) d1 = FMAXV;
      insert1(lv0, lm0, th0, d0, m, lane);
      insert1(lv1, lm1, th1, d1, m, lane);
    }
  }
  if (lane < 20) {
    knn[((size_t)b * NN + n_base) * KK + lane]     = lm0;
    knn[((size_t)b * NN + n_base + 1) * KK + lane] = lm1;
  }
}

// ---------------------------------------------------------------------------
// Kernel UV: u[b,n,o] = dot(W2[o], x_n); v[b,n,o] = dot(W1[o]-W2[o], x_n) + bias[o]
// ---------------------------------------------------------------------------
__global__ __launch_bounds__(256) void kuv(const float* __restrict__ xt,
                                           const float* __restrict__ W,
                                           const float* __restrict__ bias,
                                           float* __restrict__ u,
                                           float* __restrict__ v) {
  __shared__ float sx[64][65];
  const int b = blockIdx.y, n0 = blockIdx.x * 64;
  const int lane = threadIdx.x & 63, w = threadIdx.x >> 6;
  const float4* src = (const float4*)(xt + ((size_t)b * NN + n0) * CC);
  for (int i = threadIdx.x; i < 1024; i += 256) {
    float4 q = src[i];
    int nl = i >> 4, c4 = (i & 15) << 2;
    sx[nl][c4] = q.x; sx[nl][c4+1] = q.y; sx[nl][c4+2] = q.z; sx[nl][c4+3] = q.w;
  }
  const int o = lane;
  float w2r[64], wdr[64];
  const float4* W4 = (const float4*)W;
  #pragma unroll
  for (int c4 = 0; c4 < 16; ++c4) {
    float4 q1 = W4[o * 32 + c4];       // W1 part
    float4 q2 = W4[o * 32 + 16 + c4];  // W2 part
    w2r[c4*4]=q2.x; w2r[c4*4+1]=q2.y; w2r[c4*4+2]=q2.z; w2r[c4*4+3]=q2.w;
    wdr[c4*4]=q1.x-q2.x; wdr[c4*4+1]=q1.y-q2.y; wdr[c4*4+2]=q1.z-q2.z; wdr[c4*4+3]=q1.w-q2.w;
  }
  const float bo = bias[o];
  __syncthreads();
  for (int j = 0; j < 16; ++j) {
    int nl = w * 16 + j;
    float du = 0.f, dv = 0.f;
    #pragma unroll
    for (int c = 0; c < 64; ++c) {
      float xv = sx[nl][c];
      du += w2r[c] * xv;
      dv += wdr[c] * xv;
    }
    size_t off = ((size_t)b * NN + n0 + nl) * OO + o;
    u[off] = du;
    v[off] = dv + bo;
  }
}

// ---------------------------------------------------------------------------
// Kernel S: gather stats. Per (b,n): S1/S2 partials per channel; umax/umin.
// ---------------------------------------------------------------------------
__global__ __launch_bounds__(256) void kstats(const float* __restrict__ u,
                                              const float* __restrict__ v,
                                              const int* __restrict__ knn,
                                              float* __restrict__ umax,
                                              float* __restrict__ umin,
                                              float* __restrict__ gS) {
  const int w = threadIdx.x >> 6, lane = threadIdx.x & 63;
  const int gw = blockIdx.x * 4 + w;
  float s1 = 0.f, s2 = 0.f;
  for (int it = 0; it < 16; ++it) {
    int pair = gw * 16 + it;                 // = b*N + n
    const int* ip = knn + (size_t)pair * KK;
    float vv = v[(size_t)pair * OO + lane];
    size_t ubase = ((size_t)(pair >> 12)) * NN * OO;
    float mx = -FMAXV, mn = FMAXV;
    #pragma unroll
    for (int k = 0; k < KK; ++k) {
      int id = ip[k];
      float uu = u[ubase + (size_t)id * OO + lane];
      float y = vv + uu;
      s1 += y; s2 += y * y;
      mx = fmaxf(mx, uu); mn = fminf(mn, uu);
    }
    umax[(size_t)pair * OO + lane] = mx;
    umin[(size_t)pair * OO + lane] = mn;
  }
  __shared__ float r1[4][64], r2[4][64];
  r1[w][lane] = s1; r2[w][lane] = s2;
  __syncthreads();
  if (w == 0) {
    float a = r1[0][lane] + r1[1][lane] + r1[2][lane] + r1[3][lane];
    float c = r2[0][lane] + r2[1][lane] + r2[2][lane] + r2[3][lane];
    atomicAdd(&gS[lane], a);
    atomicAdd(&gS[64 + lane], c);
  }
}

// ---------------------------------------------------------------------------
// Kernel O: normalize, affine, relu, max over k (via umax/umin), transposed store
// ---------------------------------------------------------------------------
__global__ __launch_bounds__(256) void kout(const float* __restrict__ v,
                                            const float* __restrict__ umax,
                                            const float* __restrict__ umin,
                                            const float* __restrict__ gS,
                                            const float* __restrict__ gamma,
                                            const float* __restrict__ beta,
                                            float* __restrict__ out) {
  __shared__ float sA[64], sB[64];
  __shared__ float zt[64][65];
  const int b = blockIdx.y, n0 = blockIdx.x * 64;
  const int lane = threadIdx.x & 63, w = threadIdx.x >> 6;
  if (threadIdx.x < 64) {
    const float cnt = (float)BB * NN * KK;
    float m  = gS[lane] / cnt;
    float var = gS[64 + lane] / cnt - m * m;
    float A = gamma[lane] * rsqrtf(var + 1e-5f);
    sA[lane] = A;
    sB[lane] = beta[lane] - A * m;
  }
  __syncthreads();
  for (int j = 0; j < 16; ++j) {
    int nl = w * 16 + j;
    size_t off = ((size_t)b * NN + n0 + nl) * OO + lane;
    float A = sA[lane];
    float c0 = A * v[off] + sB[lane];
    float z = c0 + A * ((A > 0.f) ? umax[off] : umin[off]);
    zt[nl][lane] = fmaxf(z, 0.f);
  }
  __syncthreads();
  for (int j = 0; j < 16; ++j) {
    int o = w * 16 + j;
    out[((size_t)b * OO + o) * NN + n0 + lane] = zt[lane][o];
  }
}

// ---------------------------------------------------------------------------
extern "C" void kernel_launch(void* const* d_in, const int* in_sizes, int n_in,
                              void* d_out, int out_size, void* d_ws, size_t ws_size,
                              hipStream_t stream) {
  const float* x     = (const float*)d_in[0];
  const float* W     = (const float*)d_in[1];
  const float* bias  = (const float*)d_in[2];
  const float* gamma = (const float*)d_in[3];
  const float* beta  = (const float*)d_in[4];
  float* out = (float*)d_out;

  float* xt  = (float*)d_ws;          // B*N*C      = 2,097,152 f
  float* sq  = xt  + (size_t)BB*NN*CC;        // 32,768 f
  float* u   = sq  + (size_t)BB*NN;           // 2,097,152 f
  float* v   = u   + (size_t)BB*NN*OO;        // 2,097,152 f
  float* umx = v   + (size_t)BB*NN*OO;        // 2,097,152 f
  float* umn = umx + (size_t)BB*NN*OO;        // 2,097,152 f
  float* gS  = umn + (size_t)BB*NN*OO;        // 128 f
  int*   knn = (int*)(gS + 128);              // 655,360 i

  hipMemsetAsync(gS, 0, 128 * sizeof(float), stream);
  ktrans<<<dim3(NN/64, BB), 256, 0, stream>>>(x, xt, sq);
  kuv   <<<dim3(NN/64, BB), 256, 0, stream>>>(xt, W, bias, u, v);
  kknn  <<<dim3(NN/8,  BB), 256, 0, stream>>>(xt, sq, knn);
  kstats<<<dim3(512),       256, 0, stream>>>(u, v, knn, umx, umn, gS);
  kout  <<<dim3(NN/64, BB), 256, 0, stream>>>(v, umx, umn, gS, gamma, beta, out);
}